// Round 10
// baseline (148.488 us; speedup 1.0000x reference)
//
#include <hip/hip_runtime.h>
#include <hip/hip_bf16.h>
#include <hip/hip_fp16.h>
#include <cstddef>
#include <cstdint>

#define BIGV 10000000.0f
#define WPV  1.0f

#define BATCH 8
#define T1N 256
#define T2N 1024
#define CN 128
#define DN 1279          // T1+T2-1

#define FLAG_MAGIC 0x600D0000

typedef __attribute__((ext_vector_type(2))) _Float16 half2v;

// ---------------------------------------------------------------------------
// Kernel 1 (R19, unchanged): cost with F16 LDS staging + packed math.
// ---------------------------------------------------------------------------
__global__ __launch_bounds__(256) void cost_kernel(const float* __restrict__ A,
                                                   const float* __restrict__ Bf,
                                                   const int* __restrict__ lenA,
                                                   const int* __restrict__ lenB,
                                                   float* __restrict__ sk) {
    __shared__ char As[64 * 256];     // 64 rows x 128 f16 ch  (16,384 B)
    __shared__ char Bs[127 * 256];    // 127 rows x 128 f16 ch (32,512 B)

    const int b  = blockIdx.z;
    const int d0 = blockIdx.y * 64;
    const int j0 = blockIdx.x * 64;
    const int tid = threadIdx.x;

    const int dEnd = lenA[b] + lenB[b] - 2;
    if (d0 > dEnd) return;            // rows never consumed

    const float* Ab = A  + (size_t)b * T1N * CN;
    const float* Bb = Bf + (size_t)b * T2N * CN;

    const int tj = tid & 15;
    const int td = tid >> 4;
    const int brow0 = td - tj + 63;   // rows brow0+16(m-3) in [0,126]
    const int rbase = d0 - j0 - 63;

    // swizzled byte offset: row stride 256B; 16B groups rotated by row
#define SWB(row, g) (((row) << 8) + ((((g) + (row)) & 15) << 4))

    // ---- stage A: 64 rows x 32 f32-quads = 2048 -> 8 per thread ----
    #pragma unroll
    for (int i = 0; i < 8; ++i) {
        int idx = tid + i * 256;
        int row = idx >> 5;
        int q   = idx & 31;               // channels 4q..4q+3
        float4 f = *(const float4*)(Ab + (size_t)(j0 + row) * CN + (q << 2));
        half2v h0 = { (_Float16)f.x, (_Float16)f.y };
        half2v h1 = { (_Float16)f.z, (_Float16)f.w };
        char* dst = As + SWB(row, q >> 1) + ((q & 1) << 3);
        ((uint32_t*)dst)[0] = __builtin_bit_cast(uint32_t, h0);
        ((uint32_t*)dst)[1] = __builtin_bit_cast(uint32_t, h1);
    }
    // ---- stage B: 127 rows x 32 quads = 4064 -> 16 per thread (guarded) ----
    #pragma unroll
    for (int i = 0; i < 16; ++i) {
        int idx = tid + i * 256;
        if (idx < 4064) {
            int row = idx >> 5;
            int q   = idx & 31;
            int gr = rbase + row;
            gr = gr < 0 ? 0 : (gr > T2N - 1 ? T2N - 1 : gr);
            float4 f = *(const float4*)(Bb + (size_t)gr * CN + (q << 2));
            half2v h0 = { (_Float16)f.x, (_Float16)f.y };
            half2v h1 = { (_Float16)f.z, (_Float16)f.w };
            char* dst = Bs + SWB(row, q >> 1) + ((q & 1) << 3);
            ((uint32_t*)dst)[0] = __builtin_bit_cast(uint32_t, h0);
            ((uint32_t*)dst)[1] = __builtin_bit_cast(uint32_t, h1);
        }
    }
    __syncthreads();

    float acc[4][4];
    #pragma unroll
    for (int i = 0; i < 4; ++i)
        #pragma unroll
        for (int j = 0; j < 4; ++j) acc[i][j] = 0.0f;

    const half2v one2 = { (_Float16)1.0f, (_Float16)1.0f };

    for (int g = 0; g < 16; ++g) {        // 8 channels per group
        uint4 a4[4], bv[7];
        #pragma unroll
        for (int ji = 0; ji < 4; ++ji) {
            int row = tj + 16 * ji;
            a4[ji] = *(const uint4*)(As + SWB(row, g));
        }
        #pragma unroll
        for (int m = 0; m < 7; ++m) {
            int row = brow0 + 16 * (m - 3);
            bv[m] = *(const uint4*)(Bs + SWB(row, g));
        }
        #pragma unroll
        for (int dk = 0; dk < 4; ++dk) {
            #pragma unroll
            for (int ji = 0; ji < 4; ++ji) {
                uint4 au = a4[ji];
                uint4 bu = bv[dk - ji + 3];
                float a = acc[dk][ji];
                #pragma unroll
                for (int w = 0; w < 4; ++w) {
                    uint32_t ua = (&au.x)[w];
                    uint32_t ub = (&bu.x)[w];
                    half2v d2 = __builtin_bit_cast(half2v, ua)
                              - __builtin_bit_cast(half2v, ub);
                    uint32_t du = __builtin_bit_cast(uint32_t, d2) & 0x7FFF7FFFu;
#if __has_builtin(__builtin_amdgcn_fdot2)
                    a = __builtin_amdgcn_fdot2(__builtin_bit_cast(half2v, du),
                                               one2, a, false);
#else
                    half2v ad = __builtin_bit_cast(half2v, du);
                    a += (float)ad.x + (float)ad.y;
#endif
                }
                acc[dk][ji] = a;
            }
        }
    }
#undef SWB

    #pragma unroll
    for (int dk = 0; dk < 4; ++dk) {
        int d = d0 + td + 16 * dk;
        if (d < DN) {
            size_t rowoff = ((size_t)b * DN + d) * T1N;
            #pragma unroll
            for (int ji = 0; ji < 4; ++ji) {
                int j = j0 + tj + 16 * ji;
                sk[rowoff + j] = acc[dk][ji] * (1.0f / 128.0f);
            }
        }
    }
}

// ---------------------------------------------------------------------------
// Kernel 2 (R27): dp = LDS-ring prefetch (R24, proven) + PAIR doubling (R26,
// proven). Diagnosis across 5 variants: R26's VGPR_Count=80 proves regalloc
// collapsed its double-buffer (needs 128+) -> R26 tested short-chain+NO
// window (55us); R24 tested real-window+LONG chain (56us). Each alone hits
// the other bottleneck. Composition: per block = ds_read drain ~150cy +
// 16 DMA issue ~100cy + 8 PAIRs (~256 VALU issue, 8x30cy chain overlapped)
// ~550cy => ~700cy/block * 80 = ~23us core; predict dp 28-36us.
// Correctness: both halves harness-proven (absmax 0.0); only new code is
// the block-0 peel reading LDS. Row clamp kept (uniform SALU, cheap).
// ---------------------------------------------------------------------------
__device__ __forceinline__ float min3f(float a, float b, float c) {
    float d;
    asm("v_min3_f32 %0, %1, %2, %3" : "=v"(d) : "v"(a), "v"(b), "v"(c));
    return d;
}

__global__ __launch_bounds__(64, 1) void dp_ldspair_kernel(const float* __restrict__ sk,
                                                           const int* __restrict__ lenA,
                                                           const int* __restrict__ lenB,
                                                           float* __restrict__ partials,
                                                           int* __restrict__ flags,
                                                           float* __restrict__ out) {
    __shared__ char ring[3 * 16384];      // 3 slots x 16 rows x 1KB

    const int b = blockIdx.x;
    const int L = threadIdx.x;            // 0..63, columns 4L..4L+3

    const int la = __builtin_amdgcn_readfirstlane(lenA[b]);
    const int lb = __builtin_amdgcn_readfirstlane(lenB[b]);
    const int dEnd = la + lb - 2;         // in [638, 1278]
    const int kLast = dEnd >> 4;          // in [39, 79]

    // per-lane global source: lane L covers bytes [L*16, L*16+16) of each row
    const float* skb = sk + (size_t)b * DN * T1N + (L << 2);

    char* s0 = ring;
    char* s1 = ring + 16384;
    char* s2 = ring + 32768;

    // p1 = row d-1, p2 = row d-2 (invariant at every block boundary)
    float p1_0 = BIGV, p1_1 = BIGV, p1_2 = BIGV, p1_3 = BIGV;
    float p2_0 = BIGV, p2_1 = BIGV, p2_2 = BIGV, p2_3 = BIGV;
    float pp = (L == 0) ? 0.0f : BIGV;    // carry for single-step rows (0,1,tail)

#define SHFL_UP1(SRC)                                                       \
    __int_as_float(__builtin_amdgcn_update_dpp(                             \
        __float_as_int(BIGV), __float_as_int(SRC),                          \
        0x138 /* wave_shr:1 */, 0xF, 0xF, false))

#define WAITV(N) do {                                                       \
        asm volatile("s_waitcnt vmcnt(" #N ")" ::: "memory");               \
        __builtin_amdgcn_sched_barrier(0);                                  \
    } while (0)

#define WAITL0 do {                                                         \
        asm volatile("s_waitcnt lgkmcnt(0)" ::: "memory");                  \
        __builtin_amdgcn_sched_barrier(0);                                  \
    } while (0)

    // DMA one 16-row block into slot SL (no VGPR buffer -> regalloc-proof).
    // Clamp keeps the last block's rows inside sk (uniform SALU).
#define ISSUE(KB, SL) do {                                                  \
        _Pragma("unroll")                                                   \
        for (int r_ = 0; r_ < 16; ++r_) {                                   \
            int row_ = ((KB) << 4) + r_;                                    \
            row_ = row_ > DN - 1 ? DN - 1 : row_;                           \
            __builtin_amdgcn_global_load_lds(                               \
                (const __attribute__((address_space(1))) void*)(skb + (size_t)row_ * T1N), \
                (__attribute__((address_space(3))) void*)((SL) + (r_ << 10)), \
                16, 0, 0);                                                  \
        }                                                                   \
    } while (0)

#define READ16(SL)                                                          \
        float4 cc0  = *(const float4*)((SL) +  0 * 1024 + (L << 4));        \
        float4 cc1  = *(const float4*)((SL) +  1 * 1024 + (L << 4));        \
        float4 cc2  = *(const float4*)((SL) +  2 * 1024 + (L << 4));        \
        float4 cc3  = *(const float4*)((SL) +  3 * 1024 + (L << 4));        \
        float4 cc4  = *(const float4*)((SL) +  4 * 1024 + (L << 4));        \
        float4 cc5  = *(const float4*)((SL) +  5 * 1024 + (L << 4));        \
        float4 cc6  = *(const float4*)((SL) +  6 * 1024 + (L << 4));        \
        float4 cc7  = *(const float4*)((SL) +  7 * 1024 + (L << 4));        \
        float4 cc8  = *(const float4*)((SL) +  8 * 1024 + (L << 4));        \
        float4 cc9  = *(const float4*)((SL) +  9 * 1024 + (L << 4));        \
        float4 cc10 = *(const float4*)((SL) + 10 * 1024 + (L << 4));        \
        float4 cc11 = *(const float4*)((SL) + 11 * 1024 + (L << 4));        \
        float4 cc12 = *(const float4*)((SL) + 12 * 1024 + (L << 4));        \
        float4 cc13 = *(const float4*)((SL) + 13 * 1024 + (L << 4));        \
        float4 cc14 = *(const float4*)((SL) + 14 * 1024 + (L << 4));        \
        float4 cc15 = *(const float4*)((SL) + 15 * 1024 + (L << 4));

    // single step (R3/R26-proven), rotating, maintains pp carry
#define SSTEP(C4) do {                                                      \
        float4 c_ = (C4);                                                   \
        float pone_ = SHFL_UP1(p1_3);                                       \
        float w0_ = p1_0 + WPV, w1_ = p1_1 + WPV;                           \
        float w2_ = p1_2 + WPV, w3_ = p1_3 + WPV;                           \
        float wp_ = pone_ + WPV;                                            \
        float n0_ = c_.x + min3f(pp, w0_, wp_);                             \
        float n1_ = c_.y + min3f(p2_0, w1_, w0_);                           \
        float n2_ = c_.z + min3f(p2_1, w2_, w1_);                           \
        float n3_ = c_.w + min3f(p2_2, w3_, w2_);                           \
        pp = pone_;                                                         \
        p2_0 = p1_0; p2_1 = p1_1; p2_2 = p1_2; p2_3 = p1_3;                 \
        p1_0 = n0_;  p1_1 = n1_;  p1_2 = n2_;  p1_3 = n3_;                  \
    } while (0)

    // fused pair (R26-proven): rows r (CA), r+1 (CB) from (p1=r-1, p2=r-2)
#define PAIR(CA, CB) do {                                                   \
        float s1_ = SHFL_UP1(p1_3);                                         \
        float t1_ = SHFL_UP1(p2_3);                                         \
        float w0_ = p1_0 + WPV, w1_ = p1_1 + WPV;                           \
        float w2_ = p1_2 + WPV, w3_ = p1_3 + WPV;                           \
        float ws_ = s1_ + WPV;                                              \
        float q0_ = min3f(t1_,  w0_, ws_);                                  \
        float q1_ = min3f(p2_0, w1_, w0_);                                  \
        float q2_ = min3f(p2_1, w2_, w1_);                                  \
        float q3_ = min3f(p2_2, w3_, w2_);                                  \
        float4 ca_ = (CA), cb_ = (CB);                                      \
        float g0_ = ca_.x + WPV, g1_ = ca_.y + WPV;                         \
        float g2_ = ca_.z + WPV, g3_ = ca_.w + WPV;                         \
        float m20_ = g0_ + q0_, m21_ = g1_ + q1_;                           \
        float m22_ = g2_ + q2_, m23_ = g3_ + q3_;                           \
        float u_ = SHFL_UP1(m23_);                                          \
        float h0_ = min3f(s1_,  m20_, u_);                                  \
        float h1_ = min3f(p1_0, m21_, m20_);                                \
        float h2_ = min3f(p1_1, m22_, m21_);                                \
        float h3_ = min3f(p1_2, m23_, m22_);                                \
        p2_0 = ca_.x + q0_; p2_1 = ca_.y + q1_;                             \
        p2_2 = ca_.z + q2_; p2_3 = ca_.w + q3_;                             \
        p1_0 = cb_.x + h0_; p1_1 = cb_.y + h1_;                             \
        p1_2 = cb_.z + h2_; p1_3 = cb_.w + h3_;                             \
    } while (0)

#define PAIR8 do {                                                          \
        PAIR(cc0,  cc1);  PAIR(cc2,  cc3);                                  \
        PAIR(cc4,  cc5);  PAIR(cc6,  cc7);                                  \
        PAIR(cc8,  cc9);  PAIR(cc10, cc11);                                 \
        PAIR(cc12, cc13); PAIR(cc14, cc15);                                 \
    } while (0)

#define GS(C4, R) do { if ((R) <= rem) SSTEP(C4); } while (0)
#define TAIL do {                                                           \
        pp = SHFL_UP1(p2_3);  /* row d-2 col[-1] reseed (R26-proven) */     \
        GS(cc0, 0);   GS(cc1, 1);   GS(cc2, 2);   GS(cc3, 3);               \
        GS(cc4, 4);   GS(cc5, 5);   GS(cc6, 6);   GS(cc7, 7);               \
        GS(cc8, 8);   GS(cc9, 9);   GS(cc10, 10); GS(cc11, 11);             \
        GS(cc12, 12); GS(cc13, 13); GS(cc14, 14); GS(cc15, 15);             \
    } while (0)

#define ROT { char* t_ = s0; s0 = s1; s1 = s2; s2 = t_; }

    // prologue: blocks 0..2 in flight (48 outstanding <= vmcnt cap 63)
    ISSUE(0, s0);
    ISSUE(1, s1);
    ISSUE(2, s2);

    // block 0 (peel): rows 0,1 single-step (pp-seeded), rows 2..15 paired
    {
        WAITV(32);
        READ16(s0);
        WAITL0;
        ISSUE(3, s0);
        SSTEP(cc0); SSTEP(cc1);
        PAIR(cc2,  cc3);  PAIR(cc4,  cc5);
        PAIR(cc6,  cc7);  PAIR(cc8,  cc9);
        PAIR(cc10, cc11); PAIR(cc12, cc13);
        PAIR(cc14, cc15);
        ROT;
    }

    // main loop: k = 1 .. kLast-3 (issue k+3 <= kLast always valid)
    int k = 1;
    for (; k + 2 < kLast; ++k) {
        WAITV(32);
        READ16(s0);
        WAITL0;
        ISSUE(k + 3, s0);
        PAIR8;
        ROT;
    }

    // epilogue: blocks kLast-2, kLast-1 (full pairs), kLast (guarded tail)
    {
        WAITV(32);
        READ16(s0);
        WAITL0;
        PAIR8;
        ROT;
    }
    {
        WAITV(16);
        READ16(s0);
        WAITL0;
        PAIR8;
        ROT;
    }
    const int rem = dEnd & 15;
    {
        WAITV(0);
        READ16(s0);
        TAIL;
    }

    // publish partials[b] (R26-proven extraction: p1 = last committed row)
    const int tcap = la - 1;
    if (L == (tcap >> 2)) {
        const int kk = tcap & 3;
        float r = p1_0;
        if (kk == 1) r = p1_1;
        else if (kk == 2) r = p1_2;
        else if (kk == 3) r = p1_3;
        partials[b] = r;
        __threadfence();
        __hip_atomic_store(&flags[b], FLAG_MAGIC + b,
                           __ATOMIC_RELEASE, __HIP_MEMORY_SCOPE_AGENT);
    }

    // block 0: gather all 8 partials and write the final sum
    if (b == 0 && L == 0) {
        float s = 0.0f;
        for (int i = 0; i < BATCH; ++i) {
            while (__hip_atomic_load(&flags[i], __ATOMIC_ACQUIRE,
                                     __HIP_MEMORY_SCOPE_AGENT) != FLAG_MAGIC + i)
                __builtin_amdgcn_s_sleep(2);
            s += __hip_atomic_load(&partials[i], __ATOMIC_RELAXED,
                                   __HIP_MEMORY_SCOPE_AGENT);
        }
        out[0] = s;
    }
#undef ROT
#undef TAIL
#undef GS
#undef PAIR8
#undef PAIR
#undef SSTEP
#undef READ16
#undef ISSUE
#undef WAITL0
#undef WAITV
#undef SHFL_UP1
}

extern "C" void kernel_launch(void* const* d_in, const int* in_sizes, int n_in,
                              void* d_out, int out_size, void* d_ws, size_t ws_size,
                              hipStream_t stream) {
    const float* feaA = (const float*)d_in[0];
    const int*   lenA = (const int*)d_in[1];
    const float* feaB = (const float*)d_in[2];
    const int*   lenB = (const int*)d_in[3];

    float* sk       = (float*)d_ws;                       // 8*1279*256*4 B
    float* partials = (float*)((char*)d_ws + (size_t)BATCH * DN * T1N * sizeof(float));
    int*   flags    = (int*)(partials + BATCH);

    cost_kernel<<<dim3(T1N / 64, (DN + 63) / 64, BATCH), 256, 0, stream>>>(feaA, feaB, lenA, lenB, sk);
    dp_ldspair_kernel<<<BATCH, 64, 0, stream>>>(sk, lenA, lenB, partials, flags, (float*)d_out);
}

// Round 11
// 137.748 us; speedup vs baseline: 1.0780x; 1.0780x over previous
//
#include <hip/hip_runtime.h>
#include <hip/hip_bf16.h>
#include <hip/hip_fp16.h>
#include <cstddef>
#include <cstdint>

#define BIGV 10000000.0f
#define WPV  1.0f

#define BATCH 8
#define T1N 256
#define T2N 1024
#define CN 128
#define DN 1279          // T1+T2-1

#define FLAG_MAGIC 0x600D0000

typedef __attribute__((ext_vector_type(2))) _Float16 half2v;

// ---------------------------------------------------------------------------
// Kernel 1 (R19, unchanged): cost with F16 LDS staging + packed math.
// ---------------------------------------------------------------------------
__global__ __launch_bounds__(256) void cost_kernel(const float* __restrict__ A,
                                                   const float* __restrict__ Bf,
                                                   const int* __restrict__ lenA,
                                                   const int* __restrict__ lenB,
                                                   float* __restrict__ sk) {
    __shared__ char As[64 * 256];     // 64 rows x 128 f16 ch  (16,384 B)
    __shared__ char Bs[127 * 256];    // 127 rows x 128 f16 ch (32,512 B)

    const int b  = blockIdx.z;
    const int d0 = blockIdx.y * 64;
    const int j0 = blockIdx.x * 64;
    const int tid = threadIdx.x;

    const int dEnd = lenA[b] + lenB[b] - 2;
    if (d0 > dEnd) return;            // rows never consumed

    const float* Ab = A  + (size_t)b * T1N * CN;
    const float* Bb = Bf + (size_t)b * T2N * CN;

    const int tj = tid & 15;
    const int td = tid >> 4;
    const int brow0 = td - tj + 63;   // in [48,78]; rows brow0+16(m-3) in [0,126]
    const int rbase = d0 - j0 - 63;

    // swizzled byte offset: row stride 256B; 16B groups rotated by row
#define SWB(row, g) (((row) << 8) + ((((g) + (row)) & 15) << 4))

    // ---- stage A: 64 rows x 32 f32-quads = 2048 -> 8 per thread ----
    #pragma unroll
    for (int i = 0; i < 8; ++i) {
        int idx = tid + i * 256;
        int row = idx >> 5;
        int q   = idx & 31;               // channels 4q..4q+3
        float4 f = *(const float4*)(Ab + (size_t)(j0 + row) * CN + (q << 2));
        half2v h0 = { (_Float16)f.x, (_Float16)f.y };
        half2v h1 = { (_Float16)f.z, (_Float16)f.w };
        char* dst = As + SWB(row, q >> 1) + ((q & 1) << 3);
        ((uint32_t*)dst)[0] = __builtin_bit_cast(uint32_t, h0);
        ((uint32_t*)dst)[1] = __builtin_bit_cast(uint32_t, h1);
    }
    // ---- stage B: 127 rows x 32 quads = 4064 -> 16 per thread (guarded) ----
    #pragma unroll
    for (int i = 0; i < 16; ++i) {
        int idx = tid + i * 256;
        if (idx < 4064) {
            int row = idx >> 5;
            int q   = idx & 31;
            int gr = rbase + row;
            gr = gr < 0 ? 0 : (gr > T2N - 1 ? T2N - 1 : gr);
            float4 f = *(const float4*)(Bb + (size_t)gr * CN + (q << 2));
            half2v h0 = { (_Float16)f.x, (_Float16)f.y };
            half2v h1 = { (_Float16)f.z, (_Float16)f.w };
            char* dst = Bs + SWB(row, q >> 1) + ((q & 1) << 3);
            ((uint32_t*)dst)[0] = __builtin_bit_cast(uint32_t, h0);
            ((uint32_t*)dst)[1] = __builtin_bit_cast(uint32_t, h1);
        }
    }
    __syncthreads();

    float acc[4][4];
    #pragma unroll
    for (int i = 0; i < 4; ++i)
        #pragma unroll
        for (int j = 0; j < 4; ++j) acc[i][j] = 0.0f;

    const half2v one2 = { (_Float16)1.0f, (_Float16)1.0f };

    for (int g = 0; g < 16; ++g) {        // 8 channels per group
        uint4 a4[4], bv[7];
        #pragma unroll
        for (int ji = 0; ji < 4; ++ji) {
            int row = tj + 16 * ji;
            a4[ji] = *(const uint4*)(As + SWB(row, g));
        }
        #pragma unroll
        for (int m = 0; m < 7; ++m) {
            int row = brow0 + 16 * (m - 3);
            bv[m] = *(const uint4*)(Bs + SWB(row, g));
        }
        #pragma unroll
        for (int dk = 0; dk < 4; ++dk) {
            #pragma unroll
            for (int ji = 0; ji < 4; ++ji) {
                uint4 au = a4[ji];
                uint4 bu = bv[dk - ji + 3];
                float a = acc[dk][ji];
                #pragma unroll
                for (int w = 0; w < 4; ++w) {
                    uint32_t ua = (&au.x)[w];
                    uint32_t ub = (&bu.x)[w];
                    half2v d2 = __builtin_bit_cast(half2v, ua)
                              - __builtin_bit_cast(half2v, ub);
                    uint32_t du = __builtin_bit_cast(uint32_t, d2) & 0x7FFF7FFFu;
#if __has_builtin(__builtin_amdgcn_fdot2)
                    a = __builtin_amdgcn_fdot2(__builtin_bit_cast(half2v, du),
                                               one2, a, false);
#else
                    half2v ad = __builtin_bit_cast(half2v, du);
                    a += (float)ad.x + (float)ad.y;
#endif
                }
                acc[dk][ji] = a;
            }
        }
    }
#undef SWB

    #pragma unroll
    for (int dk = 0; dk < 4; ++dk) {
        int d = d0 + td + 16 * dk;
        if (d < DN) {
            size_t rowoff = ((size_t)b * DN + d) * T1N;
            #pragma unroll
            for (int ji = 0; ji < 4; ++ji) {
                int j = j0 + tj + 16 * ji;
                sk[rowoff + j] = acc[dk][ji] * (1.0f / 128.0f);
            }
        }
    }
}

// ---------------------------------------------------------------------------
// Kernel 2 (R21, restored — best measured dp at 50.4us): self-prefetching
// register double-buffer, interleaved reload, min3-folded step.
// dp ledger (6 structures): ring 52.2 / THIS 50.4 / reg-grouped 55.4 /
// LDS-DMA 56.2 / PAIR 54.7 / LDS+PAIR 61.7 -> per-step cost (~90cy) is
// structure-invariant; chain-shortening and real prefetch windows both
// made it WORSE. Further dp experiments have negative expected value.
// ---------------------------------------------------------------------------
__device__ __forceinline__ float min3f(float a, float b, float c) {
    float d;
    asm("v_min3_f32 %0, %1, %2, %3" : "=v"(d) : "v"(a), "v"(b), "v"(c));
    return d;
}

__global__ __launch_bounds__(64, 1) void dp_reg_kernel(const float* __restrict__ sk,
                                                       const int* __restrict__ lenA,
                                                       const int* __restrict__ lenB,
                                                       float* __restrict__ partials,
                                                       int* __restrict__ flags,
                                                       float* __restrict__ out) {
    const int b = blockIdx.x;
    const int L = threadIdx.x;            // 0..63, columns 4L..4L+3

    const int la = __builtin_amdgcn_readfirstlane(lenA[b]);
    const int lb = __builtin_amdgcn_readfirstlane(lenB[b]);
    const int dEnd = la + lb - 2;         // in [638, 1278]
    const int kLast = dEnd >> 4;          // final (possibly partial) 16-row block

    const char* lanep = (const char*)(sk + (size_t)b * DN * T1N) + (L << 4);

    float v1_0 = BIGV, v1_1 = BIGV, v1_2 = BIGV, v1_3 = BIGV;
    float v2_0 = BIGV, v2_1 = BIGV, v2_2 = BIGV, v2_3 = BIGV;
    float p1_prev = (L == 0) ? 0.0f : BIGV;   // pcp0 boundary column

    float4 A0, A1, A2, A3, A4, A5, A6, A7, A8, A9, A10, A11, A12, A13, A14, A15;
    float4 B0, B1, B2, B3, B4, B5, B6, B7, B8, B9, B10, B11, B12, B13, B14, B15;

#define SHFL_UP1(SRC)                                                       \
    __int_as_float(__builtin_amdgcn_update_dpp(                             \
        __float_as_int(BIGV), __float_as_int(SRC),                          \
        0x138 /* wave_shr:1 */, 0xF, 0xF, false))

    // rows > dEnd clamp to dEnd: stays inside the region cost_kernel wrote
    // (tiles with d0 > dEnd are skipped there) and inside sk bounds.
#define LOAD1(DST, KB, R) do {                                              \
        int row_ = ((KB) << 4) + (R);                                       \
        row_ = row_ > dEnd ? dEnd : row_;                                   \
        DST = *(const float4*)(lanep + (size_t)row_ * (T1N * 4));           \
    } while (0)

#define LOADALL(P, KB) do {                                                 \
        LOAD1(P##0, KB, 0);   LOAD1(P##1, KB, 1);   LOAD1(P##2, KB, 2);     \
        LOAD1(P##3, KB, 3);   LOAD1(P##4, KB, 4);   LOAD1(P##5, KB, 5);     \
        LOAD1(P##6, KB, 6);   LOAD1(P##7, KB, 7);   LOAD1(P##8, KB, 8);     \
        LOAD1(P##9, KB, 9);   LOAD1(P##10, KB, 10); LOAD1(P##11, KB, 11);   \
        LOAD1(P##12, KB, 12); LOAD1(P##13, KB, 13); LOAD1(P##14, KB, 14);   \
        LOAD1(P##15, KB, 15);                                               \
    } while (0)

    // One DP step. Identical math to R18's proven step, with
    // fmin(x, fmin(y,z)+WP) == min3(x, y+WP, z+WP) (exact; monotone rounding).
#define DP_STEP(C4) do {                                                    \
        float4 c = (C4);                                                    \
        float p1 = SHFL_UP1(v1_3);                                          \
        float w0 = v1_0 + WPV, w1 = v1_1 + WPV;                             \
        float w2 = v1_2 + WPV, w3 = v1_3 + WPV;                             \
        float wp = p1 + WPV;                                                \
        float n0 = c.x + min3f(p1_prev, w0, wp);                            \
        float n1 = c.y + min3f(v2_0, w1, w0);                               \
        float n2 = c.z + min3f(v2_1, w2, w1);                               \
        float n3 = c.w + min3f(v2_2, w3, w2);                               \
        p1_prev = p1;                                                       \
        v2_0 = v1_0; v2_1 = v1_1; v2_2 = v1_2; v2_3 = v1_3;                 \
        v1_0 = n0;   v1_1 = n1;   v1_2 = n2;   v1_3 = n3;                   \
    } while (0)

#define DP_STEP_G(C4, R) do {                                               \
        float4 c = (C4);                                                    \
        float p1 = SHFL_UP1(v1_3);                                          \
        float w0 = v1_0 + WPV, w1 = v1_1 + WPV;                             \
        float w2 = v1_2 + WPV, w3 = v1_3 + WPV;                             \
        float wp = p1 + WPV;                                                \
        float n0 = c.x + min3f(p1_prev, w0, wp);                            \
        float n1 = c.y + min3f(v2_0, w1, w0);                               \
        float n2 = c.z + min3f(v2_1, w2, w1);                               \
        float n3 = c.w + min3f(v2_2, w3, w2);                               \
        if ((R) <= rem) {                                                   \
            p1_prev = p1;                                                   \
            v2_0 = v1_0; v2_1 = v1_1; v2_2 = v1_2; v2_3 = v1_3;             \
            v1_0 = n0;   v1_1 = n1;   v1_2 = n2;   v1_3 = n3;               \
        }                                                                   \
    } while (0)

    // consume row r of this block, immediately re-issue its load for blk+2
#define STEP_RL(C4, KB, R) do { DP_STEP(C4); LOAD1(C4, KB, R); } while (0)

#define PROC_RELOAD(P, KB) do {                                             \
        STEP_RL(P##0, KB, 0);   STEP_RL(P##1, KB, 1);                       \
        STEP_RL(P##2, KB, 2);   STEP_RL(P##3, KB, 3);                       \
        STEP_RL(P##4, KB, 4);   STEP_RL(P##5, KB, 5);                       \
        STEP_RL(P##6, KB, 6);   STEP_RL(P##7, KB, 7);                       \
        STEP_RL(P##8, KB, 8);   STEP_RL(P##9, KB, 9);                       \
        STEP_RL(P##10, KB, 10); STEP_RL(P##11, KB, 11);                     \
        STEP_RL(P##12, KB, 12); STEP_RL(P##13, KB, 13);                     \
        STEP_RL(P##14, KB, 14); STEP_RL(P##15, KB, 15);                     \
    } while (0)

#define PROC_FULL(P) do {                                                   \
        DP_STEP(P##0);  DP_STEP(P##1);  DP_STEP(P##2);  DP_STEP(P##3);      \
        DP_STEP(P##4);  DP_STEP(P##5);  DP_STEP(P##6);  DP_STEP(P##7);      \
        DP_STEP(P##8);  DP_STEP(P##9);  DP_STEP(P##10); DP_STEP(P##11);     \
        DP_STEP(P##12); DP_STEP(P##13); DP_STEP(P##14); DP_STEP(P##15);     \
    } while (0)

#define PROC_GUARD(P) do {                                                  \
        DP_STEP_G(P##0, 0);   DP_STEP_G(P##1, 1);   DP_STEP_G(P##2, 2);     \
        DP_STEP_G(P##3, 3);   DP_STEP_G(P##4, 4);   DP_STEP_G(P##5, 5);     \
        DP_STEP_G(P##6, 6);   DP_STEP_G(P##7, 7);   DP_STEP_G(P##8, 8);     \
        DP_STEP_G(P##9, 9);   DP_STEP_G(P##10, 10); DP_STEP_G(P##11, 11);   \
        DP_STEP_G(P##12, 12); DP_STEP_G(P##13, 13); DP_STEP_G(P##14, 14);   \
        DP_STEP_G(P##15, 15);                                               \
    } while (0)

    // prologue: blocks 0 and 1 in flight
    LOADALL(A, 0);
    LOADALL(B, 1);

    // kLast in [39,79] so the pair loop always runs
    int k = 0;
    while (k + 1 < kLast) {               // blocks k, k+1 are full
        PROC_RELOAD(A, k + 2);
        PROC_RELOAD(B, k + 3);
        k += 2;
    }
    if (k < kLast) {                      // k == kLast-1: full A, guarded B
        PROC_FULL(A);
        const int rem = dEnd & 15;
        PROC_GUARD(B);
    } else {                              // k == kLast: guarded A
        const int rem = dEnd & 15;
        PROC_GUARD(A);
    }

    // publish partials[b] with a replay-safe magic flag (poison-robust store)
    const int tcap = la - 1;
    if (L == (tcap >> 2)) {
        const int kk = tcap & 3;
        float r = v1_0;
        if (kk == 1) r = v1_1;
        else if (kk == 2) r = v1_2;
        else if (kk == 3) r = v1_3;
        partials[b] = r;
        __threadfence();
        __hip_atomic_store(&flags[b], FLAG_MAGIC + b,
                           __ATOMIC_RELEASE, __HIP_MEMORY_SCOPE_AGENT);
    }

    // block 0: gather all 8 partials and write the final sum
    if (b == 0 && L == 0) {
        float s = 0.0f;
        for (int i = 0; i < BATCH; ++i) {
            while (__hip_atomic_load(&flags[i], __ATOMIC_ACQUIRE,
                                     __HIP_MEMORY_SCOPE_AGENT) != FLAG_MAGIC + i)
                __builtin_amdgcn_s_sleep(2);
            s += __hip_atomic_load(&partials[i], __ATOMIC_RELAXED,
                                   __HIP_MEMORY_SCOPE_AGENT);
        }
        out[0] = s;
    }
#undef PROC_GUARD
#undef PROC_FULL
#undef PROC_RELOAD
#undef STEP_RL
#undef DP_STEP_G
#undef DP_STEP
#undef LOADALL
#undef LOAD1
#undef SHFL_UP1
}

extern "C" void kernel_launch(void* const* d_in, const int* in_sizes, int n_in,
                              void* d_out, int out_size, void* d_ws, size_t ws_size,
                              hipStream_t stream) {
    const float* feaA = (const float*)d_in[0];
    const int*   lenA = (const int*)d_in[1];
    const float* feaB = (const float*)d_in[2];
    const int*   lenB = (const int*)d_in[3];

    float* sk = (float*)d_ws;                                   // 8*1279*256*4 B
    float* partials = (float*)((char*)d_ws + (size_t)BATCH * DN * T1N * sizeof(float));
    int*   flags    = (int*)(partials + BATCH);

    cost_kernel<<<dim3(T1N / 64, (DN + 63) / 64, BATCH), 256, 0, stream>>>(feaA, feaB, lenA, lenB, sk);
    dp_reg_kernel<<<BATCH, 64, 0, stream>>>(sk, lenA, lenB, partials, flags, (float*)d_out);
}

// Round 12
// 133.405 us; speedup vs baseline: 1.1131x; 1.0326x over previous
//
#include <hip/hip_runtime.h>
#include <hip/hip_bf16.h>
#include <hip/hip_fp16.h>
#include <cstddef>
#include <cstdint>

#define BIGV 10000000.0f
#define WPV  1.0f

#define BATCH 8
#define T1N 256
#define T2N 1024
#define CN 128
#define DN 1279          // T1+T2-1

#define FLAG_MAGIC 0x600D0000

typedef __attribute__((ext_vector_type(2))) _Float16 half2v;

// ---------------------------------------------------------------------------
// Kernel 1 (R28): cost re-tiled 64x64 -> 32(d)x64(j) for occupancy.
// R27 ledger: cost ~29us wall vs ~6-7us VALU-issue floor at 2.5 blocks/CU
// (LDS 48.9KB caps 3/CU) -> ~75% latency stall. New tile: Bs window 127->95
// rows (24,320B), total LDS 40,704B -> exactly 4 blocks/CU resident
// (4 x 40,960 = 160KiB). Per-cell math/f16/swizzle byte-identical; only
// geometry: dk loop 4->2, acc[2][4], stage-B 12 iters (3040 quads), bv[5],
// grid.y 40. Predict cost 29 -> 17-22us.
// ---------------------------------------------------------------------------
__global__ __launch_bounds__(256) void cost_kernel(const float* __restrict__ A,
                                                   const float* __restrict__ Bf,
                                                   const int* __restrict__ lenA,
                                                   const int* __restrict__ lenB,
                                                   float* __restrict__ sk) {
    __shared__ char As[64 * 256];     // 64 j-rows x 128 f16 ch (16,384 B)
    __shared__ char Bs[95 * 256];     // 95 rows x 128 f16 ch   (24,320 B)

    const int b  = blockIdx.z;
    const int d0 = blockIdx.y * 32;
    const int j0 = blockIdx.x * 64;
    const int tid = threadIdx.x;

    const int dEnd = lenA[b] + lenB[b] - 2;
    if (d0 > dEnd) return;            // rows never consumed

    const float* Ab = A  + (size_t)b * T1N * CN;
    const float* Bb = Bf + (size_t)b * T2N * CN;

    const int tj = tid & 15;
    const int td = tid >> 4;
    const int brow0 = td - tj + 63;   // in [48,78]; rows brow0+16(m-3) in [0,94]
    const int rbase = d0 - j0 - 63;

    // swizzled byte offset: row stride 256B; 16B groups rotated by row
#define SWB(row, g) (((row) << 8) + ((((g) + (row)) & 15) << 4))

    // ---- stage A: 64 rows x 32 f32-quads = 2048 -> 8 per thread ----
    #pragma unroll
    for (int i = 0; i < 8; ++i) {
        int idx = tid + i * 256;
        int row = idx >> 5;
        int q   = idx & 31;               // channels 4q..4q+3
        float4 f = *(const float4*)(Ab + (size_t)(j0 + row) * CN + (q << 2));
        half2v h0 = { (_Float16)f.x, (_Float16)f.y };
        half2v h1 = { (_Float16)f.z, (_Float16)f.w };
        char* dst = As + SWB(row, q >> 1) + ((q & 1) << 3);
        ((uint32_t*)dst)[0] = __builtin_bit_cast(uint32_t, h0);
        ((uint32_t*)dst)[1] = __builtin_bit_cast(uint32_t, h1);
    }
    // ---- stage B: 95 rows x 32 quads = 3040 -> 12 per thread (guarded) ----
    #pragma unroll
    for (int i = 0; i < 12; ++i) {
        int idx = tid + i * 256;
        if (idx < 3040) {
            int row = idx >> 5;
            int q   = idx & 31;
            int gr = rbase + row;
            gr = gr < 0 ? 0 : (gr > T2N - 1 ? T2N - 1 : gr);
            float4 f = *(const float4*)(Bb + (size_t)gr * CN + (q << 2));
            half2v h0 = { (_Float16)f.x, (_Float16)f.y };
            half2v h1 = { (_Float16)f.z, (_Float16)f.w };
            char* dst = Bs + SWB(row, q >> 1) + ((q & 1) << 3);
            ((uint32_t*)dst)[0] = __builtin_bit_cast(uint32_t, h0);
            ((uint32_t*)dst)[1] = __builtin_bit_cast(uint32_t, h1);
        }
    }
    __syncthreads();

    float acc[2][4];
    #pragma unroll
    for (int i = 0; i < 2; ++i)
        #pragma unroll
        for (int j = 0; j < 4; ++j) acc[i][j] = 0.0f;

    const half2v one2 = { (_Float16)1.0f, (_Float16)1.0f };

    for (int g = 0; g < 16; ++g) {        // 8 channels per group
        uint4 a4[4], bv[5];
        #pragma unroll
        for (int ji = 0; ji < 4; ++ji) {
            int row = tj + 16 * ji;
            a4[ji] = *(const uint4*)(As + SWB(row, g));
        }
        #pragma unroll
        for (int m = 0; m < 5; ++m) {
            int row = brow0 + 16 * (m - 3);
            bv[m] = *(const uint4*)(Bs + SWB(row, g));
        }
        #pragma unroll
        for (int dk = 0; dk < 2; ++dk) {
            #pragma unroll
            for (int ji = 0; ji < 4; ++ji) {
                uint4 au = a4[ji];
                uint4 bu = bv[dk - ji + 3];
                float a = acc[dk][ji];
                #pragma unroll
                for (int w = 0; w < 4; ++w) {
                    uint32_t ua = (&au.x)[w];
                    uint32_t ub = (&bu.x)[w];
                    half2v d2 = __builtin_bit_cast(half2v, ua)
                              - __builtin_bit_cast(half2v, ub);
                    uint32_t du = __builtin_bit_cast(uint32_t, d2) & 0x7FFF7FFFu;
#if __has_builtin(__builtin_amdgcn_fdot2)
                    a = __builtin_amdgcn_fdot2(__builtin_bit_cast(half2v, du),
                                               one2, a, false);
#else
                    half2v ad = __builtin_bit_cast(half2v, du);
                    a += (float)ad.x + (float)ad.y;
#endif
                }
                acc[dk][ji] = a;
            }
        }
    }
#undef SWB

    #pragma unroll
    for (int dk = 0; dk < 2; ++dk) {
        int d = d0 + td + 16 * dk;
        if (d < DN) {
            size_t rowoff = ((size_t)b * DN + d) * T1N;
            #pragma unroll
            for (int ji = 0; ji < 4; ++ji) {
                int j = j0 + tj + 16 * ji;
                sk[rowoff + j] = acc[dk][ji] * (1.0f / 128.0f);
            }
        }
    }
}

// ---------------------------------------------------------------------------
// Kernel 2 (R21, frozen — best measured dp at 50.4us): self-prefetching
// register double-buffer, interleaved reload, min3-folded step.
// dp ledger (6 structures): ring 52.2 / THIS 50.4 / reg-grouped 55.4 /
// LDS-DMA 56.2 / PAIR 54.7 / LDS+PAIR 61.7. R11 replay: L2-hot == HBM-cold
// time -> data-path-independent; per-row ~95cy is lone-wave issue floor.
// dp is FROZEN.
// ---------------------------------------------------------------------------
__device__ __forceinline__ float min3f(float a, float b, float c) {
    float d;
    asm("v_min3_f32 %0, %1, %2, %3" : "=v"(d) : "v"(a), "v"(b), "v"(c));
    return d;
}

__global__ __launch_bounds__(64, 1) void dp_reg_kernel(const float* __restrict__ sk,
                                                       const int* __restrict__ lenA,
                                                       const int* __restrict__ lenB,
                                                       float* __restrict__ partials,
                                                       int* __restrict__ flags,
                                                       float* __restrict__ out) {
    const int b = blockIdx.x;
    const int L = threadIdx.x;            // 0..63, columns 4L..4L+3

    const int la = __builtin_amdgcn_readfirstlane(lenA[b]);
    const int lb = __builtin_amdgcn_readfirstlane(lenB[b]);
    const int dEnd = la + lb - 2;         // in [638, 1278]
    const int kLast = dEnd >> 4;          // final (possibly partial) 16-row block

    const char* lanep = (const char*)(sk + (size_t)b * DN * T1N) + (L << 4);

    float v1_0 = BIGV, v1_1 = BIGV, v1_2 = BIGV, v1_3 = BIGV;
    float v2_0 = BIGV, v2_1 = BIGV, v2_2 = BIGV, v2_3 = BIGV;
    float p1_prev = (L == 0) ? 0.0f : BIGV;   // pcp0 boundary column

    float4 A0, A1, A2, A3, A4, A5, A6, A7, A8, A9, A10, A11, A12, A13, A14, A15;
    float4 B0, B1, B2, B3, B4, B5, B6, B7, B8, B9, B10, B11, B12, B13, B14, B15;

#define SHFL_UP1(SRC)                                                       \
    __int_as_float(__builtin_amdgcn_update_dpp(                             \
        __float_as_int(BIGV), __float_as_int(SRC),                          \
        0x138 /* wave_shr:1 */, 0xF, 0xF, false))

    // rows > dEnd clamp to dEnd: stays inside the region cost_kernel wrote
    // (tiles with d0 > dEnd are skipped there) and inside sk bounds.
#define LOAD1(DST, KB, R) do {                                              \
        int row_ = ((KB) << 4) + (R);                                       \
        row_ = row_ > dEnd ? dEnd : row_;                                   \
        DST = *(const float4*)(lanep + (size_t)row_ * (T1N * 4));           \
    } while (0)

#define LOADALL(P, KB) do {                                                 \
        LOAD1(P##0, KB, 0);   LOAD1(P##1, KB, 1);   LOAD1(P##2, KB, 2);     \
        LOAD1(P##3, KB, 3);   LOAD1(P##4, KB, 4);   LOAD1(P##5, KB, 5);     \
        LOAD1(P##6, KB, 6);   LOAD1(P##7, KB, 7);   LOAD1(P##8, KB, 8);     \
        LOAD1(P##9, KB, 9);   LOAD1(P##10, KB, 10); LOAD1(P##11, KB, 11);   \
        LOAD1(P##12, KB, 12); LOAD1(P##13, KB, 13); LOAD1(P##14, KB, 14);   \
        LOAD1(P##15, KB, 15);                                               \
    } while (0)

    // One DP step. Identical math to R18's proven step, with
    // fmin(x, fmin(y,z)+WP) == min3(x, y+WP, z+WP) (exact; monotone rounding).
#define DP_STEP(C4) do {                                                    \
        float4 c = (C4);                                                    \
        float p1 = SHFL_UP1(v1_3);                                          \
        float w0 = v1_0 + WPV, w1 = v1_1 + WPV;                             \
        float w2 = v1_2 + WPV, w3 = v1_3 + WPV;                             \
        float wp = p1 + WPV;                                                \
        float n0 = c.x + min3f(p1_prev, w0, wp);                            \
        float n1 = c.y + min3f(v2_0, w1, w0);                               \
        float n2 = c.z + min3f(v2_1, w2, w1);                               \
        float n3 = c.w + min3f(v2_2, w3, w2);                               \
        p1_prev = p1;                                                       \
        v2_0 = v1_0; v2_1 = v1_1; v2_2 = v1_2; v2_3 = v1_3;                 \
        v1_0 = n0;   v1_1 = n1;   v1_2 = n2;   v1_3 = n3;                   \
    } while (0)

#define DP_STEP_G(C4, R) do {                                               \
        float4 c = (C4);                                                    \
        float p1 = SHFL_UP1(v1_3);                                          \
        float w0 = v1_0 + WPV, w1 = v1_1 + WPV;                             \
        float w2 = v1_2 + WPV, w3 = v1_3 + WPV;                             \
        float wp = p1 + WPV;                                                \
        float n0 = c.x + min3f(p1_prev, w0, wp);                            \
        float n1 = c.y + min3f(v2_0, w1, w0);                               \
        float n2 = c.z + min3f(v2_1, w2, w1);                               \
        float n3 = c.w + min3f(v2_2, w3, w2);                               \
        if ((R) <= rem) {                                                   \
            p1_prev = p1;                                                   \
            v2_0 = v1_0; v2_1 = v1_1; v2_2 = v1_2; v2_3 = v1_3;             \
            v1_0 = n0;   v1_1 = n1;   v1_2 = n2;   v1_3 = n3;               \
        }                                                                   \
    } while (0)

    // consume row r of this block, immediately re-issue its load for blk+2
#define STEP_RL(C4, KB, R) do { DP_STEP(C4); LOAD1(C4, KB, R); } while (0)

#define PROC_RELOAD(P, KB) do {                                             \
        STEP_RL(P##0, KB, 0);   STEP_RL(P##1, KB, 1);                       \
        STEP_RL(P##2, KB, 2);   STEP_RL(P##3, KB, 3);                       \
        STEP_RL(P##4, KB, 4);   STEP_RL(P##5, KB, 5);                       \
        STEP_RL(P##6, KB, 6);   STEP_RL(P##7, KB, 7);                       \
        STEP_RL(P##8, KB, 8);   STEP_RL(P##9, KB, 9);                       \
        STEP_RL(P##10, KB, 10); STEP_RL(P##11, KB, 11);                     \
        STEP_RL(P##12, KB, 12); STEP_RL(P##13, KB, 13);                     \
        STEP_RL(P##14, KB, 14); STEP_RL(P##15, KB, 15);                     \
    } while (0)

#define PROC_FULL(P) do {                                                   \
        DP_STEP(P##0);  DP_STEP(P##1);  DP_STEP(P##2);  DP_STEP(P##3);      \
        DP_STEP(P##4);  DP_STEP(P##5);  DP_STEP(P##6);  DP_STEP(P##7);      \
        DP_STEP(P##8);  DP_STEP(P##9);  DP_STEP(P##10); DP_STEP(P##11);     \
        DP_STEP(P##12); DP_STEP(P##13); DP_STEP(P##14); DP_STEP(P##15);     \
    } while (0)

#define PROC_GUARD(P) do {                                                  \
        DP_STEP_G(P##0, 0);   DP_STEP_G(P##1, 1);   DP_STEP_G(P##2, 2);     \
        DP_STEP_G(P##3, 3);   DP_STEP_G(P##4, 4);   DP_STEP_G(P##5, 5);     \
        DP_STEP_G(P##6, 6);   DP_STEP_G(P##7, 7);   DP_STEP_G(P##8, 8);     \
        DP_STEP_G(P##9, 9);   DP_STEP_G(P##10, 10); DP_STEP_G(P##11, 11);   \
        DP_STEP_G(P##12, 12); DP_STEP_G(P##13, 13); DP_STEP_G(P##14, 14);   \
        DP_STEP_G(P##15, 15);                                               \
    } while (0)

    // prologue: blocks 0 and 1 in flight
    LOADALL(A, 0);
    LOADALL(B, 1);

    // kLast in [39,79] so the pair loop always runs
    int k = 0;
    while (k + 1 < kLast) {               // blocks k, k+1 are full
        PROC_RELOAD(A, k + 2);
        PROC_RELOAD(B, k + 3);
        k += 2;
    }
    if (k < kLast) {                      // k == kLast-1: full A, guarded B
        PROC_FULL(A);
        const int rem = dEnd & 15;
        PROC_GUARD(B);
    } else {                              // k == kLast: guarded A
        const int rem = dEnd & 15;
        PROC_GUARD(A);
    }

    // publish partials[b] with a replay-safe magic flag (poison-robust store)
    const int tcap = la - 1;
    if (L == (tcap >> 2)) {
        const int kk = tcap & 3;
        float r = v1_0;
        if (kk == 1) r = v1_1;
        else if (kk == 2) r = v1_2;
        else if (kk == 3) r = v1_3;
        partials[b] = r;
        __threadfence();
        __hip_atomic_store(&flags[b], FLAG_MAGIC + b,
                           __ATOMIC_RELEASE, __HIP_MEMORY_SCOPE_AGENT);
    }

    // block 0: gather all 8 partials and write the final sum
    if (b == 0 && L == 0) {
        float s = 0.0f;
        for (int i = 0; i < BATCH; ++i) {
            while (__hip_atomic_load(&flags[i], __ATOMIC_ACQUIRE,
                                     __HIP_MEMORY_SCOPE_AGENT) != FLAG_MAGIC + i)
                __builtin_amdgcn_s_sleep(2);
            s += __hip_atomic_load(&partials[i], __ATOMIC_RELAXED,
                                   __HIP_MEMORY_SCOPE_AGENT);
        }
        out[0] = s;
    }
#undef PROC_GUARD
#undef PROC_FULL
#undef PROC_RELOAD
#undef STEP_RL
#undef DP_STEP_G
#undef DP_STEP
#undef LOADALL
#undef LOAD1
#undef SHFL_UP1
}

extern "C" void kernel_launch(void* const* d_in, const int* in_sizes, int n_in,
                              void* d_out, int out_size, void* d_ws, size_t ws_size,
                              hipStream_t stream) {
    const float* feaA = (const float*)d_in[0];
    const int*   lenA = (const int*)d_in[1];
    const float* feaB = (const float*)d_in[2];
    const int*   lenB = (const int*)d_in[3];

    float* sk = (float*)d_ws;                                   // 8*1279*256*4 B
    float* partials = (float*)((char*)d_ws + (size_t)BATCH * DN * T1N * sizeof(float));
    int*   flags    = (int*)(partials + BATCH);

    cost_kernel<<<dim3(T1N / 64, (DN + 31) / 32, BATCH), 256, 0, stream>>>(feaA, feaB, lenA, lenB, sk);
    dp_reg_kernel<<<BATCH, 64, 0, stream>>>(sk, lenA, lenB, partials, flags, (float*)d_out);
}